// Round 1
// 1349.111 us; speedup vs baseline: 1.0724x; 1.0724x over previous
//
#include <hip/hip_runtime.h>
#include <math.h>
#include <stdint.h>

typedef unsigned short u16;
typedef __attribute__((ext_vector_type(8))) short bf8;      // 8 bf16 MFMA operand (4 VGPR)
typedef __attribute__((ext_vector_type(8))) unsigned short us8;
typedef __attribute__((ext_vector_type(4))) float f4;

#define B_  32
#define T_  577
#define D_  768
#define BT  18464
#define H3  2304
#define HD  3072
#define NH  12
#define DH  64
#define TT  332929ull        // T_*T_
#define TP  608              // T_ padded to mult of 32 (K dim of AV)
#define LNEPS 1e-6f

// async global->LDS, 16B per lane; dest = wave-uniform base + lane*16
#define GLOAD_LDS16(gp, lp)                                                \
  __builtin_amdgcn_global_load_lds(                                       \
      (const __attribute__((address_space(1))) void*)(gp),                 \
      (__attribute__((address_space(3))) void*)(unsigned)(uintptr_t)(lp),  \
      16, 0, 0)

__device__ __forceinline__ u16 f2bf(float f) {
  unsigned int u = __float_as_uint(f);
  u += 0x7fffu + ((u >> 16) & 1u);       // round-to-nearest-even
  return (u16)(u >> 16);
}

// ---------------- LayerNorm fp32 -> bf16 ----------------
__global__ __launch_bounds__(256) void ln_bf16(const float* __restrict__ x,
    const float* __restrict__ w, const float* __restrict__ b, u16* __restrict__ y) {
  int row = blockIdx.x;
  const float* xr = x + (size_t)row * D_;
  int t = threadIdx.x;
  float v0 = xr[t], v1 = xr[t + 256], v2 = xr[t + 512];
  float s  = v0 + v1 + v2;
  float ss = v0*v0 + v1*v1 + v2*v2;
  #pragma unroll
  for (int o = 32; o >= 1; o >>= 1) {
    s  += __shfl_xor(s,  o, 64);
    ss += __shfl_xor(ss, o, 64);
  }
  __shared__ float rs_[4], rss_[4];
  int wid = t >> 6;
  if ((t & 63) == 0) { rs_[wid] = s; rss_[wid] = ss; }
  __syncthreads();
  s  = rs_[0]  + rs_[1]  + rs_[2]  + rs_[3];
  ss = rss_[0] + rss_[1] + rss_[2] + rss_[3];
  float mu  = s * (1.0f / D_);
  float var = ss * (1.0f / D_) - mu * mu;
  float rstd = rsqrtf(var + LNEPS);
  u16* yr = y + (size_t)row * D_;
  yr[t]       = f2bf((v0 - mu) * rstd * w[t]       + b[t]);
  yr[t + 256] = f2bf((v1 - mu) * rstd * w[t + 256] + b[t + 256]);
  yr[t + 512] = f2bf((v2 - mu) * rstd * w[t + 512] + b[t + 512]);
}

// ---------------- weight fp32 [K,N] -> bf16 transposed [N,K] ----------------
__global__ __launch_bounds__(256) void wconv(const float* __restrict__ W,
    u16* __restrict__ Wt, int K, int N) {
  __shared__ float tile[64][68];
  int n0 = blockIdx.x * 64, k0 = blockIdx.y * 64;
  int t = threadIdx.x;
  #pragma unroll
  for (int r = 0; r < 4; ++r) {
    int flat = r * 256 + t;
    int kr = flat >> 4, g = flat & 15;
    float4 v = *(const float4*)(W + (size_t)(k0 + kr) * N + n0 + g * 4);
    *(float4*)&tile[kr][g * 4] = v;
  }
  __syncthreads();
  #pragma unroll
  for (int r = 0; r < 2; ++r) {
    int flat = r * 256 + t;
    int n = flat >> 3, g2 = flat & 7;
    us8 o;
    #pragma unroll
    for (int j = 0; j < 8; ++j) o[j] = f2bf(tile[g2 * 8 + j][n]);
    *(us8*)(Wt + (size_t)(n0 + n) * K + k0 + g2 * 8) = o;
  }
}

// ---------------- build Vt [z][128][TP] from qkvbf V-slot ----------------
__global__ __launch_bounds__(256) void vt_prep(const u16* __restrict__ qkvbf,
    u16* __restrict__ Vt) {
  int z = blockIdx.z;
  int bb = z / NH, h = z - bb * NH;
  u16* out = Vt + (size_t)z * 128 * TP;
  int k0 = blockIdx.x * 64;
  int t = threadIdx.x;
  if (blockIdx.y == 1) {
    #pragma unroll
    for (int r = 0; r < 2; ++r) {
      int flat = r * 256 + t;
      int n = 64 + (flat >> 3), g = flat & 7;
      int kc = k0 + g * 8;
      if (kc < TP) {
        us8 zz = {0,0,0,0,0,0,0,0};
        *(us8*)(out + (size_t)n * TP + kc) = zz;
      }
    }
    return;
  }
  __shared__ u16 tile[64][72];
  const u16* src = qkvbf + ((size_t)bb * T_) * H3 + 2 * D_ + h * DH;
  #pragma unroll
  for (int r = 0; r < 2; ++r) {
    int flat = r * 256 + t;
    int kr = flat >> 3, g = flat & 7;
    int gk = k0 + kr;
    us8 v = {0,0,0,0,0,0,0,0};
    if (gk < T_) v = *(const us8*)(src + (size_t)gk * H3 + g * 8);
    *(us8*)&tile[kr][g * 8] = v;
  }
  __syncthreads();
  #pragma unroll
  for (int r = 0; r < 2; ++r) {
    int flat = r * 256 + t;
    int n = flat >> 3, g2 = flat & 7;
    int kc = k0 + g2 * 8;
    if (kc < TP) {
      us8 o;
      #pragma unroll
      for (int j = 0; j < 8; ++j) o[j] = tile[g2 * 8 + j][n];
      *(us8*)(out + (size_t)n * TP + kc) = o;
    }
  }
}

// ---------------- softmax over heads; fp32 dp -> bf16 P (padded to TP) ----------------
__global__ __launch_bounds__(256) void softmax_pad(const float* __restrict__ dp,
    u16* __restrict__ P) {
  int bb = blockIdx.y;
  int i = blockIdx.x * 256 + threadIdx.x;
  if (i >= T_ * TP) return;
  int qq = i / TP, kp = i - qq * TP;
  u16* Pb = P + (size_t)bb * NH * T_ * TP + (size_t)qq * TP + kp;
  if (kp >= T_) {
    #pragma unroll
    for (int h = 0; h < NH; ++h) Pb[(size_t)h * T_ * TP] = 0;
    return;
  }
  const float* db = dp + (size_t)bb * NH * TT + (size_t)qq * T_ + kp;
  float v[NH];
  float m = -1e30f;
  #pragma unroll
  for (int h = 0; h < NH; ++h) { v[h] = db[(size_t)h * TT]; m = fmaxf(m, v[h]); }
  float s = 0.f;
  #pragma unroll
  for (int h = 0; h < NH; ++h) { v[h] = expf(v[h] - m); s += v[h]; }
  float inv = 1.0f / s;
  #pragma unroll
  for (int h = 0; h < NH; ++h) Pb[(size_t)h * T_ * TP] = f2bf(v[h] * inv);
}

// ---------------- bf16 MFMA GEMM: 128x128 tile (kept for attention GEMMs) ----------------
// EPI: 3 = *scale -> f32 C      4 = plain -> bf16 C
template <int EPI>
__global__ __launch_bounds__(256) void gemm_bf16(
    const u16* __restrict__ Abase, int lda,
    const u16* __restrict__ Bbase, int ldb,
    const float* __restrict__ bias,
    const float* __restrict__ res, int ldr,
    float* __restrict__ Cf, u16* __restrict__ Cb, int ldc,
    int M, int Nst, int Nb, int K, float scale, int bmode) {
  __shared__ u16 As[128 * 32];
  __shared__ u16 Bs[128 * 32];
  int z = blockIdx.z;
  size_t aoff = 0, boff = 0, coff = 0;
  if (bmode == 1) {
    int bb = z / NH, h = z - bb * NH;
    aoff = (size_t)bb * T_ * H3 + (size_t)h * DH;
    boff = aoff + D_;
    coff = (size_t)z * TT;
  } else if (bmode == 2) {
    int bb = z / NH, h = z - bb * NH;
    aoff = (size_t)z * T_ * TP;
    boff = (size_t)z * 128 * TP;
    coff = (size_t)bb * T_ * H3 + (size_t)h * DH;
  }
  const u16* A  = Abase + aoff;
  const u16* Bt = Bbase + boff;

  int bx = blockIdx.x, by = blockIdx.y;
  int m_base = by * 128, n_base = bx * 128;

  int tid = threadIdx.x;
  int wid = tid >> 6, lane = tid & 63;
  int wm = (wid >> 1) * 64, wn = (wid & 1) * 64;
  int lm = lane & 15, q = lane >> 4;
  int srow = tid >> 2, sg = tid & 3;

  int gm0 = m_base + srow;       gm0 = gm0 < M ? gm0 : M - 1;
  int gm1 = m_base + 64 + srow;  gm1 = gm1 < M ? gm1 : M - 1;
  int gn0 = n_base + srow;       gn0 = gn0 < Nb ? gn0 : Nb - 1;
  int gn1 = n_base + 64 + srow;  gn1 = gn1 < Nb ? gn1 : Nb - 1;
  const u16* a0 = A  + (size_t)gm0 * lda + sg * 8;
  const u16* a1 = A  + (size_t)gm1 * lda + sg * 8;
  const u16* b0 = Bt + (size_t)gn0 * ldb + sg * 8;
  const u16* b1 = Bt + (size_t)gn1 * ldb + sg * 8;
  u16* lA = As + wid * 512;   // wave-uniform base; lane dest = +lane*16B
  u16* lB = Bs + wid * 512;

  f4 acc[4][4] = {};

  for (int kc = 0; kc < K; kc += 32) {
    GLOAD_LDS16(a0 + kc, lA);
    GLOAD_LDS16(a1 + kc, lA + 2048);
    GLOAD_LDS16(b0 + kc, lB);
    GLOAD_LDS16(b1 + kc, lB + 2048);
    __syncthreads();
    bf8 af[4], bfr[4];
    #pragma unroll
    for (int mt = 0; mt < 4; ++mt)
      af[mt] = *(const bf8*)&As[(wm + mt * 16 + lm) * 32 + q * 8];
    #pragma unroll
    for (int nt = 0; nt < 4; ++nt)
      bfr[nt] = *(const bf8*)&Bs[(wn + nt * 16 + lm) * 32 + q * 8];
    #pragma unroll
    for (int mt = 0; mt < 4; ++mt)
      #pragma unroll
      for (int nt = 0; nt < 4; ++nt)
        acc[mt][nt] = __builtin_amdgcn_mfma_f32_16x16x32_bf16(af[mt], bfr[nt], acc[mt][nt], 0, 0, 0);
    __syncthreads();
  }

  // epilogue: C/D layout col = lane&15, row = quad*4 + reg
  #pragma unroll
  for (int mt = 0; mt < 4; ++mt) {
    #pragma unroll
    for (int i = 0; i < 4; ++i) {
      int grow = m_base + wm + mt * 16 + q * 4 + i;
      if (grow >= M) continue;
      #pragma unroll
      for (int nt = 0; nt < 4; ++nt) {
        int gcol = n_base + wn + nt * 16 + lm;
        if (gcol >= Nst) continue;
        float v = acc[mt][nt][i];
        if (EPI == 3) {
          Cf[coff + (size_t)grow * ldc + gcol] = v * scale;
        } else {
          Cb[coff + (size_t)grow * ldc + gcol] = f2bf(v);
        }
      }
    }
  }
}

// ================= 256x256 8-phase bf16 GEMM (T2+T3+T4+T5) =================
// BM=BN=256, BK=64, 8 waves (2Mx4N), per-wave 128x64 output.
// LDS 128KiB: A = 2buf x 2half x [128 rows][64 cols bf16], B same after.
// XOR-granule swizzle: LDS granule slot gs (16B) of row r holds logical
// granule gs^(r&7); staged via pre-swizzled GLOBAL source (rule #21),
// read with the same XOR -> ds_read_b128 conflict-free (2-way max).
// Counted vmcnt(4): B-halves staged 2 K-tiles ahead (phases 3,4),
// A-halves 1 K-tile ahead (phases 1,2); every half staged strictly after
// its last reader's barrier. vmcnt(4) at phase 4 forces tile t+1 landed.
// EPI: 0 = bias -> bf16   1 = bias+res -> f32   2 = bias+gelu -> bf16
#define STG(P0, P1, RB, T) do {                              \
    const u16* _s0 = (P0) + (size_t)(T) * 64;                \
    const u16* _s1 = (P1) + (size_t)(T) * 64;                \
    GLOAD_LDS16(_s0, lds + (RB) + f0 * 8);                   \
    GLOAD_LDS16(_s1, lds + (RB) + f0 * 8 + 4096);            \
  } while (0)

#define PH_TOP() do {                                        \
    __builtin_amdgcn_sched_barrier(0);                       \
    __builtin_amdgcn_s_barrier();                            \
    asm volatile("s_waitcnt lgkmcnt(0)" ::: "memory");       \
    __builtin_amdgcn_sched_barrier(0);                       \
  } while (0)

#define PH_END() do {                                        \
    __builtin_amdgcn_s_barrier();                            \
    __builtin_amdgcn_sched_barrier(0);                       \
  } while (0)

#define MFMA_Q(AG, BG) do {                                  \
    __builtin_amdgcn_s_setprio(1);                           \
    _Pragma("unroll")                                        \
    for (int mti = 0; mti < 4; ++mti) {                      \
      _Pragma("unroll")                                      \
      for (int nti = 0; nti < 2; ++nti) {                    \
        acc[(AG)*4+mti][(BG)*2+nti] =                        \
          __builtin_amdgcn_mfma_f32_16x16x32_bf16(af[mti][0], bfr[BG][nti][0], acc[(AG)*4+mti][(BG)*2+nti], 0, 0, 0); \
        acc[(AG)*4+mti][(BG)*2+nti] =                        \
          __builtin_amdgcn_mfma_f32_16x16x32_bf16(af[mti][1], bfr[BG][nti][1], acc[(AG)*4+mti][(BG)*2+nti], 0, 0, 0); \
      }                                                      \
    }                                                        \
    __builtin_amdgcn_s_setprio(0);                           \
  } while (0)

template <int EPI>
__global__ __launch_bounds__(512, 2) void gemm256(
    const u16* __restrict__ A, int lda,
    const u16* __restrict__ Bt, int ldb,
    const float* __restrict__ bias,
    const float* __restrict__ res, int ldr,
    float* __restrict__ Cf, u16* __restrict__ Cb, int ldc,
    int M, int N, int K) {
  __shared__ u16 lds[65536];           // 128 KiB
  const int NKT = K >> 6;              // K-tiles of 64

  // bijective XCD swizzle (m204): contiguous wgid chunk per XCD
  int gx = gridDim.x;
  int nwg = gx * (int)gridDim.y;
  int orig = blockIdx.y * gx + blockIdx.x;
  int qq = nwg >> 3, rr = nwg & 7;
  int xcd = orig & 7, loc = orig >> 3;
  int wg = (xcd < rr ? xcd * (qq + 1) : rr * (qq + 1) + (xcd - rr) * qq) + loc;
  int by = wg / gx, bx = wg - by * gx;
  int m_base = by * 256, n_base = bx * 256;

  int tid = threadIdx.x;
  int wid = tid >> 6, lane = tid & 63;
  int wr = wid >> 2, wc = wid & 3;     // wave = (row-half, col-quarter)
  int lm = lane & 15, q = lane >> 4;

  // ---- staging: thread covers rows r0 and r0+64 of a 128-row half,
  //      granule g0 = (f&7) ^ (row&7)  (inverse-swizzled source) ----
  int f0 = tid;
  int r0 = f0 >> 3, g0 = (f0 & 7) ^ (r0 & 7);
  int M1 = M - 1;
  int ra0 = m_base + r0;        ra0 = ra0 < M1 ? ra0 : M1;
  int ra1 = m_base + 64  + r0;  ra1 = ra1 < M1 ? ra1 : M1;
  int ra2 = m_base + 128 + r0;  ra2 = ra2 < M1 ? ra2 : M1;
  int ra3 = m_base + 192 + r0;  ra3 = ra3 < M1 ? ra3 : M1;
  const u16* pa00 = A + (size_t)ra0 * lda + g0 * 8;
  const u16* pa01 = A + (size_t)ra1 * lda + g0 * 8;
  const u16* pa10 = A + (size_t)ra2 * lda + g0 * 8;
  const u16* pa11 = A + (size_t)ra3 * lda + g0 * 8;
  const u16* pb00 = Bt + (size_t)(n_base + r0)       * ldb + g0 * 8;
  const u16* pb01 = Bt + (size_t)(n_base + 64  + r0) * ldb + g0 * 8;
  const u16* pb10 = Bt + (size_t)(n_base + 128 + r0) * ldb + g0 * 8;
  const u16* pb11 = Bt + (size_t)(n_base + 192 + r0) * ldb + g0 * 8;

  // ---- ds_read bases (u16 units); row&7 == lm&7 for all fragments ----
  int ge0 = (q ^ (lm & 7)) * 8;        // kc=0 granule offset
  int ge1 = ge0 ^ 32;                  // kc=1: granule ^4 -> *8 = ^32
  int aoffb = wr * 8192 + lm * 64;
  int boffb = 32768 + (wc >> 1) * 8192 + ((wc & 1) * 64 + lm) * 64;

  f4 acc[8][4] = {};
  bf8 af[4][2], bfr[2][2][2];

  // ---- prologue: B(0), A(0), B(1) staged; keep B(1) in flight ----
  STG(pb00, pb01, 32768, 0);
  STG(pb10, pb11, 32768 + 8192, 0);
  STG(pa00, pa01, 0, 0);
  STG(pa10, pa11, 8192, 0);
  int t1 = NKT > 1 ? 1 : 0;
  STG(pb00, pb01, 32768 + 16384, t1);
  STG(pb10, pb11, 32768 + 16384 + 8192, t1);
  asm volatile("s_waitcnt vmcnt(4)" ::: "memory");  // tile 0 fully landed
  __builtin_amdgcn_s_barrier();
  __builtin_amdgcn_sched_barrier(0);

  for (int t = 0; t < NKT; ++t) {
    int p = t & 1, pn = p ^ 1;
    int tA = (t + 1 < NKT) ? t + 1 : NKT - 1;
    int tB = (t + 2 < NKT) ? t + 2 : NKT - 1;
    const u16* la = lds + p * 16384 + aoffb;
    const u16* lb = lds + p * 16384 + boffb;

    // phase 1: read A(ag0)+B(bg0); stage A-half0(t+1) -> other buf
    #pragma unroll
    for (int mti = 0; mti < 4; ++mti) {
      af[mti][0] = *(const bf8*)(la + mti * 1024 + ge0);
      af[mti][1] = *(const bf8*)(la + mti * 1024 + ge1);
    }
    #pragma unroll
    for (int nti = 0; nti < 2; ++nti) {
      bfr[0][nti][0] = *(const bf8*)(lb + nti * 1024 + ge0);
      bfr[0][nti][1] = *(const bf8*)(lb + nti * 1024 + ge1);
    }
    STG(pa00, pa01, pn * 16384, tA);
    PH_TOP();
    MFMA_Q(0, 0);
    PH_END();

    // phase 2: read B(bg1); stage A-half1(t+1)
    #pragma unroll
    for (int nti = 0; nti < 2; ++nti) {
      bfr[1][nti][0] = *(const bf8*)(lb + 2048 + nti * 1024 + ge0);
      bfr[1][nti][1] = *(const bf8*)(lb + 2048 + nti * 1024 + ge1);
    }
    STG(pa10, pa11, pn * 16384 + 8192, tA);
    PH_TOP();
    MFMA_Q(0, 1);
    PH_END();

    // phase 3: read A(ag1); stage B-half0(t+2) -> same buf (B consumed by ph2)
    #pragma unroll
    for (int mti = 0; mti < 4; ++mti) {
      af[mti][0] = *(const bf8*)(la + 4096 + mti * 1024 + ge0);
      af[mti][1] = *(const bf8*)(la + 4096 + mti * 1024 + ge1);
    }
    STG(pb00, pb01, 32768 + p * 16384, tB);
    PH_TOP();
    MFMA_Q(1, 1);
    PH_END();

    // phase 4: stage B-half1(t+2); counted vmcnt -> tile t+1 landed
    STG(pb10, pb11, 32768 + p * 16384 + 8192, tB);
    PH_TOP();
    MFMA_Q(1, 0);
    asm volatile("s_waitcnt vmcnt(4)" ::: "memory");
    PH_END();
  }

  asm volatile("s_waitcnt vmcnt(0)" ::: "memory");  // drain before LDS dealloc

  // ---- epilogue: wave tile rows wr*128, cols wc*64 ----
  #pragma unroll
  for (int mt = 0; mt < 8; ++mt) {
    #pragma unroll
    for (int i = 0; i < 4; ++i) {
      int grow = m_base + wr * 128 + mt * 16 + q * 4 + i;
      if (grow >= M) continue;
      #pragma unroll
      for (int nt = 0; nt < 4; ++nt) {
        int gcol = n_base + wc * 64 + nt * 16 + lm;
        float v = acc[mt][nt][i];
        if (EPI == 0) {
          v += bias[gcol];
          Cb[(size_t)grow * ldc + gcol] = f2bf(v);
        } else if (EPI == 1) {
          v += bias[gcol] + res[(size_t)grow * ldr + gcol];
          Cf[(size_t)grow * ldc + gcol] = v;
        } else {
          v += bias[gcol];
          v = 0.5f * v * (1.0f + erff(v * 0.70710678118654752f));
          Cb[(size_t)grow * ldc + gcol] = f2bf(v);
        }
      }
    }
  }
}

// ---------------- launch ----------------
extern "C" void kernel_launch(void* const* d_in, const int* in_sizes, int n_in,
                              void* d_out, int out_size, void* d_ws, size_t ws_size,
                              hipStream_t stream) {
  const float* x     = (const float*)d_in[0];
  const float* ln1w  = (const float*)d_in[1];
  const float* ln1b  = (const float*)d_in[2];
  const float* qkvw  = (const float*)d_in[3];
  const float* qkvb  = (const float*)d_in[4];
  const float* projw = (const float*)d_in[5];
  const float* projb = (const float*)d_in[6];
  const float* ln2w  = (const float*)d_in[7];
  const float* ln2b  = (const float*)d_in[8];
  const float* fc1w  = (const float*)d_in[9];
  const float* fc1b  = (const float*)d_in[10];
  const float* fc2w  = (const float*)d_in[11];
  const float* fc2b  = (const float*)d_in[12];
  float* out = (float*)d_out;

  // ---- workspace layout ----
  u16* qkvwT  = (u16*)d_ws;                       // [2304][768]
  u16* projwT = qkvwT  + (size_t)H3 * D_;         // [768][768]
  u16* fc1wT  = projwT + (size_t)D_ * D_;         // [3072][768]
  u16* fc2wT  = fc1wT  + (size_t)HD * D_;         // [768][3072]
  char* chunk = (char*)(fc2wT + (size_t)D_ * HD);
  const size_t wbytes = ((size_t)H3 * D_ + (size_t)D_ * D_ + 2 * (size_t)HD * D_) * 2;
  size_t avail = ws_size - wbytes;

  const size_t per_batch =
      (size_t)T_ * D_ * 2 + (size_t)T_ * H3 * 2 + (size_t)NH * TT * 4 +
      (size_t)NH * T_ * TP * 2 + (size_t)NH * 128 * TP * 2;
  int NB = (int)(avail / per_batch);
  if (NB < 1)  NB = 1;
  if (NB > B_) NB = B_;

  u16*   ybf   = (u16*)chunk;
  u16*   qkvbf = ybf + (size_t)NB * T_ * D_;
  float* dp    = (float*)(qkvbf + (size_t)NB * T_ * H3);
  u16*   P     = (u16*)(dp + (size_t)NB * NH * TT);
  u16*   Vt    = P + (size_t)NB * NH * T_ * TP;

  // ---- weights: fp32 [K,N] -> bf16 [N,K] ----
  wconv<<<dim3(H3 / 64, D_ / 64), 256, 0, stream>>>(qkvw, qkvwT, D_, H3);
  wconv<<<dim3(D_ / 64, D_ / 64), 256, 0, stream>>>(projw, projwT, D_, D_);
  wconv<<<dim3(HD / 64, D_ / 64), 256, 0, stream>>>(fc1w, fc1wT, D_, HD);
  wconv<<<dim3(D_ / 64, HD / 64), 256, 0, stream>>>(fc2w, fc2wT, HD, D_);

  // ---- attention branch, chunked over batches ----
  for (int b0 = 0; b0 < B_; b0 += NB) {
    int nb = (B_ - b0 < NB) ? (B_ - b0) : NB;
    int rows = nb * T_;
    int mb = (rows + 255) / 256;
    const float* xc = x + (size_t)b0 * T_ * D_;
    float* outc = out + (size_t)b0 * T_ * D_;

    ln_bf16<<<rows, 256, 0, stream>>>(xc, ln1w, ln1b, ybf);
    gemm256<0><<<dim3(H3 / 256, mb), 512, 0, stream>>>(
        ybf, D_, qkvwT, D_, qkvb, nullptr, 0, nullptr, qkvbf, H3,
        rows, H3, D_);
    vt_prep<<<dim3(10, 2, nb * NH), 256, 0, stream>>>(qkvbf, Vt);
    gemm_bf16<3><<<dim3(5, 5, nb * NH), 256, 0, stream>>>(
        qkvbf, H3, qkvbf, H3, nullptr, nullptr, 0, dp, nullptr, T_,
        T_, T_, T_, DH, 0.125f, 1);
    softmax_pad<<<dim3((T_ * TP + 255) / 256, nb), 256, 0, stream>>>(dp, P);
    gemm_bf16<4><<<dim3(1, 5, nb * NH), 256, 0, stream>>>(
        P, TP, Vt, TP, nullptr, nullptr, 0, nullptr, qkvbf, H3,
        T_, DH, 128, TP, 1.f, 2);
    gemm256<1><<<dim3(D_ / 256, mb), 512, 0, stream>>>(
        qkvbf, H3, projwT, D_, projb, xc, D_, outc, nullptr, D_,
        rows, D_, D_);
  }

  // ---- MLP branch, chunked over rows ----
  size_t chrows = avail / ((size_t)D_ * 2 + (size_t)HD * 2);
  int CH = (chrows > (size_t)BT) ? BT : (int)chrows;
  CH &= ~127;
  if (CH < 128) CH = 128;
  for (int r0 = 0; r0 < BT; r0 += CH) {
    int rows = (BT - r0 < CH) ? (BT - r0) : CH;
    int mb = (rows + 255) / 256;
    float* oc = out + (size_t)r0 * D_;
    u16* y2  = (u16*)chunk;
    u16* hdn = y2 + (size_t)CH * D_;

    ln_bf16<<<rows, 256, 0, stream>>>(oc, ln2w, ln2b, y2);
    gemm256<2><<<dim3(HD / 256, mb), 512, 0, stream>>>(
        y2, D_, fc1wT, D_, fc1b, nullptr, 0, nullptr, hdn, HD,
        rows, HD, D_);
    gemm256<1><<<dim3(D_ / 256, mb), 512, 0, stream>>>(
        hdn, HD, fc2wT, HD, fc2b, oc, D_, oc, nullptr, D_,
        rows, D_, HD);
  }
}

// Round 2
// 1111.153 us; speedup vs baseline: 1.3020x; 1.2142x over previous
//
#include <hip/hip_runtime.h>
#include <math.h>
#include <stdint.h>

typedef unsigned short u16;
typedef __attribute__((ext_vector_type(8))) short bf8;      // 8 bf16 MFMA operand (4 VGPR)
typedef __attribute__((ext_vector_type(8))) unsigned short us8;
typedef __attribute__((ext_vector_type(4))) float f4;

#define B_  32
#define T_  577
#define D_  768
#define BT  18464
#define H3  2304
#define HD  3072
#define NH  12
#define DH  64
#define TT  332929ull        // T_*T_
#define TP  608              // T_ padded to mult of 32 (K dim of AV)
#define LNEPS 1e-6f

// async global->LDS, 16B per lane; dest = wave-uniform base + lane*16
#define GLOAD_LDS16(gp, lp)                                                \
  __builtin_amdgcn_global_load_lds(                                       \
      (const __attribute__((address_space(1))) void*)(gp),                 \
      (__attribute__((address_space(3))) void*)(unsigned)(uintptr_t)(lp),  \
      16, 0, 0)

__device__ __forceinline__ u16 f2bf(float f) {
  unsigned int u = __float_as_uint(f);
  u += 0x7fffu + ((u >> 16) & 1u);       // round-to-nearest-even
  return (u16)(u >> 16);
}

// fast erf (Abramowitz-Stegun 7.1.26, max abs err 1.5e-7 << bf16 ulp)
__device__ __forceinline__ float gelu_fast(float v) {
  float ax = fabsf(v) * 0.70710678118654752f;
  float t  = __builtin_amdgcn_rcpf(fmaf(0.3275911f, ax, 1.0f));
  float p  = fmaf(fmaf(fmaf(fmaf(1.061405429f, t, -1.453152027f), t,
                            1.421413741f), t, -0.284496736f), t, 0.254829592f);
  float er = 1.0f - p * t * __expf(-ax * ax);
  er = v < 0.0f ? -er : er;
  return 0.5f * v * (1.0f + er);
}

// ---------------- LayerNorm fp32 -> bf16 ----------------
__global__ __launch_bounds__(256) void ln_bf16(const float* __restrict__ x,
    const float* __restrict__ w, const float* __restrict__ b, u16* __restrict__ y) {
  int row = blockIdx.x;
  const float* xr = x + (size_t)row * D_;
  int t = threadIdx.x;
  float v0 = xr[t], v1 = xr[t + 256], v2 = xr[t + 512];
  float s  = v0 + v1 + v2;
  float ss = v0*v0 + v1*v1 + v2*v2;
  #pragma unroll
  for (int o = 32; o >= 1; o >>= 1) {
    s  += __shfl_xor(s,  o, 64);
    ss += __shfl_xor(ss, o, 64);
  }
  __shared__ float rs_[4], rss_[4];
  int wid = t >> 6;
  if ((t & 63) == 0) { rs_[wid] = s; rss_[wid] = ss; }
  __syncthreads();
  s  = rs_[0]  + rs_[1]  + rs_[2]  + rs_[3];
  ss = rss_[0] + rss_[1] + rss_[2] + rss_[3];
  float mu  = s * (1.0f / D_);
  float var = ss * (1.0f / D_) - mu * mu;
  float rstd = rsqrtf(var + LNEPS);
  u16* yr = y + (size_t)row * D_;
  yr[t]       = f2bf((v0 - mu) * rstd * w[t]       + b[t]);
  yr[t + 256] = f2bf((v1 - mu) * rstd * w[t + 256] + b[t + 256]);
  yr[t + 512] = f2bf((v2 - mu) * rstd * w[t + 512] + b[t + 512]);
}

// ---------------- weight fp32 [K,N] -> bf16 transposed [N,K] ----------------
__global__ __launch_bounds__(256) void wconv(const float* __restrict__ W,
    u16* __restrict__ Wt, int K, int N) {
  __shared__ float tile[64][68];
  int n0 = blockIdx.x * 64, k0 = blockIdx.y * 64;
  int t = threadIdx.x;
  #pragma unroll
  for (int r = 0; r < 4; ++r) {
    int flat = r * 256 + t;
    int kr = flat >> 4, g = flat & 15;
    float4 v = *(const float4*)(W + (size_t)(k0 + kr) * N + n0 + g * 4);
    *(float4*)&tile[kr][g * 4] = v;
  }
  __syncthreads();
  #pragma unroll
  for (int r = 0; r < 2; ++r) {
    int flat = r * 256 + t;
    int n = flat >> 3, g2 = flat & 7;
    us8 o;
    #pragma unroll
    for (int j = 0; j < 8; ++j) o[j] = f2bf(tile[g2 * 8 + j][n]);
    *(us8*)(Wt + (size_t)(n0 + n) * K + k0 + g2 * 8) = o;
  }
}

// ---------------- build Vt [z][128][TP] from qkvbf V-slot ----------------
__global__ __launch_bounds__(256) void vt_prep(const u16* __restrict__ qkvbf,
    u16* __restrict__ Vt) {
  int z = blockIdx.z;
  int bb = z / NH, h = z - bb * NH;
  u16* out = Vt + (size_t)z * 128 * TP;
  int k0 = blockIdx.x * 64;
  int t = threadIdx.x;
  if (blockIdx.y == 1) {
    #pragma unroll
    for (int r = 0; r < 2; ++r) {
      int flat = r * 256 + t;
      int n = 64 + (flat >> 3), g = flat & 7;
      int kc = k0 + g * 8;
      if (kc < TP) {
        us8 zz = {0,0,0,0,0,0,0,0};
        *(us8*)(out + (size_t)n * TP + kc) = zz;
      }
    }
    return;
  }
  __shared__ u16 tile[64][72];
  const u16* src = qkvbf + ((size_t)bb * T_) * H3 + 2 * D_ + h * DH;
  #pragma unroll
  for (int r = 0; r < 2; ++r) {
    int flat = r * 256 + t;
    int kr = flat >> 3, g = flat & 7;
    int gk = k0 + kr;
    us8 v = {0,0,0,0,0,0,0,0};
    if (gk < T_) v = *(const us8*)(src + (size_t)gk * H3 + g * 8);
    *(us8*)&tile[kr][g * 8] = v;
  }
  __syncthreads();
  #pragma unroll
  for (int r = 0; r < 2; ++r) {
    int flat = r * 256 + t;
    int n = flat >> 3, g2 = flat & 7;
    int kc = k0 + g2 * 8;
    if (kc < TP) {
      us8 o;
      #pragma unroll
      for (int j = 0; j < 8; ++j) o[j] = tile[g2 * 8 + j][n];
      *(us8*)(out + (size_t)n * TP + kc) = o;
    }
  }
}

// ---------------- softmax over heads; fp32 dp -> bf16 P (padded to TP) ----------------
__global__ __launch_bounds__(256) void softmax_pad(const float* __restrict__ dp,
    u16* __restrict__ P) {
  int bb = blockIdx.y;
  int i = blockIdx.x * 256 + threadIdx.x;
  if (i >= T_ * TP) return;
  int qq = i / TP, kp = i - qq * TP;
  u16* Pb = P + (size_t)bb * NH * T_ * TP + (size_t)qq * TP + kp;
  if (kp >= T_) {
    #pragma unroll
    for (int h = 0; h < NH; ++h) Pb[(size_t)h * T_ * TP] = 0;
    return;
  }
  const float* db = dp + (size_t)bb * NH * TT + (size_t)qq * T_ + kp;
  float v[NH];
  float m = -1e30f;
  #pragma unroll
  for (int h = 0; h < NH; ++h) { v[h] = db[(size_t)h * TT]; m = fmaxf(m, v[h]); }
  float s = 0.f;
  #pragma unroll
  for (int h = 0; h < NH; ++h) { v[h] = expf(v[h] - m); s += v[h]; }
  float inv = 1.0f / s;
  #pragma unroll
  for (int h = 0; h < NH; ++h) Pb[(size_t)h * T_ * TP] = f2bf(v[h] * inv);
}

// ---------------- bf16 MFMA GEMM: 128x128 tile (attention GEMMs) ----------------
// EPI: 3 = *scale -> f32 C      4 = plain -> bf16 C
template <int EPI>
__global__ __launch_bounds__(256) void gemm_bf16(
    const u16* __restrict__ Abase, int lda,
    const u16* __restrict__ Bbase, int ldb,
    const float* __restrict__ bias,
    const float* __restrict__ res, int ldr,
    float* __restrict__ Cf, u16* __restrict__ Cb, int ldc,
    int M, int Nst, int Nb, int K, float scale, int bmode) {
  __shared__ u16 As[128 * 32];
  __shared__ u16 Bs[128 * 32];
  int z = blockIdx.z;
  size_t aoff = 0, boff = 0, coff = 0;
  if (bmode == 1) {
    int bb = z / NH, h = z - bb * NH;
    aoff = (size_t)bb * T_ * H3 + (size_t)h * DH;
    boff = aoff + D_;
    coff = (size_t)z * TT;
  } else if (bmode == 2) {
    int bb = z / NH, h = z - bb * NH;
    aoff = (size_t)z * T_ * TP;
    boff = (size_t)z * 128 * TP;
    coff = (size_t)bb * T_ * H3 + (size_t)h * DH;
  }
  const u16* A  = Abase + aoff;
  const u16* Bt = Bbase + boff;

  int bx = blockIdx.x, by = blockIdx.y;
  int m_base = by * 128, n_base = bx * 128;

  int tid = threadIdx.x;
  int wid = tid >> 6, lane = tid & 63;
  int wm = (wid >> 1) * 64, wn = (wid & 1) * 64;
  int lm = lane & 15, q = lane >> 4;
  int srow = tid >> 2, sg = tid & 3;

  int gm0 = m_base + srow;       gm0 = gm0 < M ? gm0 : M - 1;
  int gm1 = m_base + 64 + srow;  gm1 = gm1 < M ? gm1 : M - 1;
  int gn0 = n_base + srow;       gn0 = gn0 < Nb ? gn0 : Nb - 1;
  int gn1 = n_base + 64 + srow;  gn1 = gn1 < Nb ? gn1 : Nb - 1;
  const u16* a0 = A  + (size_t)gm0 * lda + sg * 8;
  const u16* a1 = A  + (size_t)gm1 * lda + sg * 8;
  const u16* b0 = Bt + (size_t)gn0 * ldb + sg * 8;
  const u16* b1 = Bt + (size_t)gn1 * ldb + sg * 8;
  u16* lA = As + wid * 512;   // wave-uniform base; lane dest = +lane*16B
  u16* lB = Bs + wid * 512;

  f4 acc[4][4] = {};

  for (int kc = 0; kc < K; kc += 32) {
    GLOAD_LDS16(a0 + kc, lA);
    GLOAD_LDS16(a1 + kc, lA + 2048);
    GLOAD_LDS16(b0 + kc, lB);
    GLOAD_LDS16(b1 + kc, lB + 2048);
    __syncthreads();
    bf8 af[4], bfr[4];
    #pragma unroll
    for (int mt = 0; mt < 4; ++mt)
      af[mt] = *(const bf8*)&As[(wm + mt * 16 + lm) * 32 + q * 8];
    #pragma unroll
    for (int nt = 0; nt < 4; ++nt)
      bfr[nt] = *(const bf8*)&Bs[(wn + nt * 16 + lm) * 32 + q * 8];
    #pragma unroll
    for (int mt = 0; mt < 4; ++mt)
      #pragma unroll
      for (int nt = 0; nt < 4; ++nt)
        acc[mt][nt] = __builtin_amdgcn_mfma_f32_16x16x32_bf16(af[mt], bfr[nt], acc[mt][nt], 0, 0, 0);
    __syncthreads();
  }

  // epilogue: C/D layout col = lane&15, row = quad*4 + reg
  #pragma unroll
  for (int mt = 0; mt < 4; ++mt) {
    #pragma unroll
    for (int i = 0; i < 4; ++i) {
      int grow = m_base + wm + mt * 16 + q * 4 + i;
      if (grow >= M) continue;
      #pragma unroll
      for (int nt = 0; nt < 4; ++nt) {
        int gcol = n_base + wn + nt * 16 + lm;
        if (gcol >= Nst) continue;
        float v = acc[mt][nt][i];
        if (EPI == 3) {
          Cf[coff + (size_t)grow * ldc + gcol] = v * scale;
        } else {
          Cb[coff + (size_t)grow * ldc + gcol] = f2bf(v);
        }
      }
    }
  }
}

// ============ 128x128 BK=64 double-buffered pipelined GEMM ============
// 4 waves (2x2), per-wave 64x64 (acc[4][4]); LDS 64 KiB -> 2 blocks/CU so
// independent blocks overlap each other's barrier/LDS/epilogue stalls.
// Granule XOR-swizzle (slot s of row r holds granule s^(r&7)); staged via
// inverse-swizzled GLOBAL source, linear gload_lds dest (rule #21).
// Counted vmcnt(8): tile t+1's 8 loads issued at top of iter t; wait only
// for tile t's 8. Two barriers per K-tile.
// EPI: 0 = bias -> bf16   1 = bias+res -> f32   2 = bias+gelu -> bf16
template <int EPI>
__global__ __launch_bounds__(256, 2) void gemm128(
    const u16* __restrict__ A, int lda,
    const u16* __restrict__ Bt, int ldb,
    const float* __restrict__ bias,
    const float* __restrict__ res, int ldr,
    float* __restrict__ Cf, u16* __restrict__ Cb, int ldc,
    int M, int K) {
  __shared__ u16 lds[32768];           // A: [2][8192] @0, B: [2][8192] @16384
  const int NKT = K >> 6;

  // bijective XCD swizzle (m204)
  int gx = gridDim.x;
  int nwg = gx * (int)gridDim.y;
  int orig = blockIdx.y * gx + blockIdx.x;
  int qq = nwg >> 3, rr = nwg & 7;
  int xcd = orig & 7, loc = orig >> 3;
  int wg = (xcd < rr ? xcd * (qq + 1) : rr * (qq + 1) + (xcd - rr) * qq) + loc;
  int by = wg / gx, bx = wg - by * gx;
  int m_base = by * 128, n_base = bx * 128;

  int tid = threadIdx.x;
  int wid = tid >> 6, lane = tid & 63;
  int wr = wid >> 1, wc = wid & 1;
  int lm = lane & 15, q = lane >> 4;

  // staging: thread -> row r0+32u, slot tid&7 holds granule g0 = (tid&7)^(r0&7)
  int r0 = tid >> 3, g0 = (tid & 7) ^ (r0 & 7);
  int M1 = M - 1;
  int ra0 = m_base + r0;       ra0 = ra0 < M1 ? ra0 : M1;
  int ra1 = m_base + 32 + r0;  ra1 = ra1 < M1 ? ra1 : M1;
  int ra2 = m_base + 64 + r0;  ra2 = ra2 < M1 ? ra2 : M1;
  int ra3 = m_base + 96 + r0;  ra3 = ra3 < M1 ? ra3 : M1;
  const u16* pa0 = A + (size_t)ra0 * lda + g0 * 8;
  const u16* pa1 = A + (size_t)ra1 * lda + g0 * 8;
  const u16* pa2 = A + (size_t)ra2 * lda + g0 * 8;
  const u16* pa3 = A + (size_t)ra3 * lda + g0 * 8;
  const u16* pb0 = Bt + (size_t)(n_base + r0)      * ldb + g0 * 8;
  const u16* pb1 = Bt + (size_t)(n_base + 32 + r0) * ldb + g0 * 8;
  const u16* pb2 = Bt + (size_t)(n_base + 64 + r0) * ldb + g0 * 8;
  const u16* pb3 = Bt + (size_t)(n_base + 96 + r0) * ldb + g0 * 8;

  auto STAGE = [&](int abuf, int bbuf, int t) {
    size_t ko = (size_t)t * 64;
    GLOAD_LDS16(pa0 + ko, lds + abuf + tid * 8);
    GLOAD_LDS16(pa1 + ko, lds + abuf + 2048 + tid * 8);
    GLOAD_LDS16(pa2 + ko, lds + abuf + 4096 + tid * 8);
    GLOAD_LDS16(pa3 + ko, lds + abuf + 6144 + tid * 8);
    GLOAD_LDS16(pb0 + ko, lds + bbuf + tid * 8);
    GLOAD_LDS16(pb1 + ko, lds + bbuf + 2048 + tid * 8);
    GLOAD_LDS16(pb2 + ko, lds + bbuf + 4096 + tid * 8);
    GLOAD_LDS16(pb3 + ko, lds + bbuf + 6144 + tid * 8);
  };

  // ds_read addressing: row&7 == lm&7 for all fragments
  int ge0 = (q ^ (lm & 7)) * 8;        // kc granule 0..3 ; ^32 for k-half 1
  int aoffb = (wr * 64 + lm) * 64;
  int boffb = 16384 + (wc * 64 + lm) * 64;

  f4 acc[4][4] = {};

  STAGE(0, 16384, 0);                  // prologue: tile 0 -> buf 0

  for (int t = 0; t < NKT; ++t) {
    int p = t & 1;
    int Ab = p * 8192, Bb = p * 8192;  // Bb is added to boffb (has +16384)
    int An = (p ^ 1) * 8192, Bn = 16384 + (p ^ 1) * 8192;
    int tN = t + 1 < NKT ? t + 1 : t;

    STAGE(An, Bn, tN);                           // tile t+1 -> other bufs
    asm volatile("s_waitcnt vmcnt(8)" ::: "memory");  // tile t landed (mine)
    __builtin_amdgcn_s_barrier();                // tile t landed (all waves)
    __builtin_amdgcn_sched_barrier(0);

    bf8 af[2][4], bfr[2][4];
    #pragma unroll
    for (int mt = 0; mt < 4; ++mt) {
      af[0][mt] = *(const bf8*)(lds + Ab + aoffb + mt * 1024 + ge0);
      af[1][mt] = *(const bf8*)(lds + Ab + aoffb + mt * 1024 + (ge0 ^ 32));
    }
    #pragma unroll
    for (int nt = 0; nt < 4; ++nt) {
      bfr[0][nt] = *(const bf8*)(lds + Bb + boffb + nt * 1024 + ge0);
      bfr[1][nt] = *(const bf8*)(lds + Bb + boffb + nt * 1024 + (ge0 ^ 32));
    }
    asm volatile("s_waitcnt lgkmcnt(0)" ::: "memory");
    __builtin_amdgcn_sched_barrier(0);

    __builtin_amdgcn_s_setprio(1);
    #pragma unroll
    for (int kk = 0; kk < 2; ++kk)
      #pragma unroll
      for (int mt = 0; mt < 4; ++mt)
        #pragma unroll
        for (int nt = 0; nt < 4; ++nt)
          acc[mt][nt] = __builtin_amdgcn_mfma_f32_16x16x32_bf16(
              af[kk][mt], bfr[kk][nt], acc[mt][nt], 0, 0, 0);
    __builtin_amdgcn_s_setprio(0);

    __builtin_amdgcn_s_barrier();                // reads done before overwrite
    __builtin_amdgcn_sched_barrier(0);
  }

  asm volatile("s_waitcnt vmcnt(0)" ::: "memory");   // drain dummy restage

  // epilogue: C/D layout col = lane&15, row = quad*4 + reg
  #pragma unroll
  for (int mt = 0; mt < 4; ++mt) {
    #pragma unroll
    for (int i = 0; i < 4; ++i) {
      int grow = m_base + wr * 64 + mt * 16 + q * 4 + i;
      if (grow >= M) continue;
      #pragma unroll
      for (int nt = 0; nt < 4; ++nt) {
        int gcol = n_base + wc * 64 + nt * 16 + lm;
        float v = acc[mt][nt][i];
        if (EPI == 0) {
          v += bias[gcol];
          Cb[(size_t)grow * ldc + gcol] = f2bf(v);
        } else if (EPI == 1) {
          v += bias[gcol] + res[(size_t)grow * ldr + gcol];
          Cf[(size_t)grow * ldc + gcol] = v;
        } else {
          v += bias[gcol];
          Cb[(size_t)grow * ldc + gcol] = f2bf(gelu_fast(v));
        }
      }
    }
  }
}

// ---------------- launch ----------------
extern "C" void kernel_launch(void* const* d_in, const int* in_sizes, int n_in,
                              void* d_out, int out_size, void* d_ws, size_t ws_size,
                              hipStream_t stream) {
  const float* x     = (const float*)d_in[0];
  const float* ln1w  = (const float*)d_in[1];
  const float* ln1b  = (const float*)d_in[2];
  const float* qkvw  = (const float*)d_in[3];
  const float* qkvb  = (const float*)d_in[4];
  const float* projw = (const float*)d_in[5];
  const float* projb = (const float*)d_in[6];
  const float* ln2w  = (const float*)d_in[7];
  const float* ln2b  = (const float*)d_in[8];
  const float* fc1w  = (const float*)d_in[9];
  const float* fc1b  = (const float*)d_in[10];
  const float* fc2w  = (const float*)d_in[11];
  const float* fc2b  = (const float*)d_in[12];
  float* out = (float*)d_out;

  // ---- workspace layout ----
  u16* qkvwT  = (u16*)d_ws;                       // [2304][768]
  u16* projwT = qkvwT  + (size_t)H3 * D_;         // [768][768]
  u16* fc1wT  = projwT + (size_t)D_ * D_;         // [3072][768]
  u16* fc2wT  = fc1wT  + (size_t)HD * D_;         // [768][3072]
  char* chunk = (char*)(fc2wT + (size_t)D_ * HD);
  const size_t wbytes = ((size_t)H3 * D_ + (size_t)D_ * D_ + 2 * (size_t)HD * D_) * 2;
  size_t avail = ws_size - wbytes;

  const size_t per_batch =
      (size_t)T_ * D_ * 2 + (size_t)T_ * H3 * 2 + (size_t)NH * TT * 4 +
      (size_t)NH * T_ * TP * 2 + (size_t)NH * 128 * TP * 2;
  int NB = (int)(avail / per_batch);
  if (NB < 1)  NB = 1;
  if (NB > B_) NB = B_;

  u16*   ybf   = (u16*)chunk;
  u16*   qkvbf = ybf + (size_t)NB * T_ * D_;
  float* dp    = (float*)(qkvbf + (size_t)NB * T_ * H3);
  u16*   P     = (u16*)(dp + (size_t)NB * NH * TT);
  u16*   Vt    = P + (size_t)NB * NH * T_ * TP;

  // ---- weights: fp32 [K,N] -> bf16 [N,K] ----
  wconv<<<dim3(H3 / 64, D_ / 64), 256, 0, stream>>>(qkvw, qkvwT, D_, H3);
  wconv<<<dim3(D_ / 64, D_ / 64), 256, 0, stream>>>(projw, projwT, D_, D_);
  wconv<<<dim3(HD / 64, D_ / 64), 256, 0, stream>>>(fc1w, fc1wT, D_, HD);
  wconv<<<dim3(D_ / 64, HD / 64), 256, 0, stream>>>(fc2w, fc2wT, HD, D_);

  // ---- attention branch, chunked over batches ----
  for (int b0 = 0; b0 < B_; b0 += NB) {
    int nb = (B_ - b0 < NB) ? (B_ - b0) : NB;
    int rows = nb * T_;
    int mb = (rows + 127) / 128;
    const float* xc = x + (size_t)b0 * T_ * D_;
    float* outc = out + (size_t)b0 * T_ * D_;

    ln_bf16<<<rows, 256, 0, stream>>>(xc, ln1w, ln1b, ybf);
    gemm128<0><<<dim3(H3 / 128, mb), 256, 0, stream>>>(
        ybf, D_, qkvwT, D_, qkvb, nullptr, 0, nullptr, qkvbf, H3,
        rows, D_);
    vt_prep<<<dim3(10, 2, nb * NH), 256, 0, stream>>>(qkvbf, Vt);
    gemm_bf16<3><<<dim3(5, 5, nb * NH), 256, 0, stream>>>(
        qkvbf, H3, qkvbf, H3, nullptr, nullptr, 0, dp, nullptr, T_,
        T_, T_, T_, DH, 0.125f, 1);
    softmax_pad<<<dim3((T_ * TP + 255) / 256, nb), 256, 0, stream>>>(dp, P);
    gemm_bf16<4><<<dim3(1, 5, nb * NH), 256, 0, stream>>>(
        P, TP, Vt, TP, nullptr, nullptr, 0, nullptr, qkvbf, H3,
        T_, DH, 128, TP, 1.f, 2);
    gemm128<1><<<dim3(D_ / 128, mb), 256, 0, stream>>>(
        qkvbf, H3, projwT, D_, projb, xc, D_, outc, nullptr, D_,
        rows, D_);
  }

  // ---- MLP branch, chunked over rows ----
  size_t chrows = avail / ((size_t)D_ * 2 + (size_t)HD * 2);
  int CH = (chrows > (size_t)BT) ? BT : (int)chrows;
  CH &= ~127;
  if (CH < 128) CH = 128;
  for (int r0 = 0; r0 < BT; r0 += CH) {
    int rows = (BT - r0 < CH) ? (BT - r0) : CH;
    int mb = (rows + 127) / 128;
    float* oc = out + (size_t)r0 * D_;
    u16* y2  = (u16*)chunk;
    u16* hdn = y2 + (size_t)CH * D_;

    ln_bf16<<<rows, 256, 0, stream>>>(oc, ln2w, ln2b, y2);
    gemm128<2><<<dim3(HD / 128, mb), 256, 0, stream>>>(
        y2, D_, fc1wT, D_, fc1b, nullptr, 0, nullptr, hdn, HD,
        rows, D_);
    gemm128<1><<<dim3(D_ / 128, mb), 256, 0, stream>>>(
        hdn, HD, fc2wT, HD, fc2b, oc, D_, oc, nullptr, D_,
        rows, HD);
  }
}